// Round 9
// baseline (32.969 us; speedup 1.0000x reference)
//
#include <hip/hip_runtime.h>
#include <hip/hip_bf16.h>

// MoE: out[b] = inp[b] @ weight[gate[b]].T
// inp: [4096,512] f32, gate: [4096] int, weight: [32,512,512] f32, out: [4096,512] f32
// Round 9: r6 shell + global_load_lds DMA staging (f32 tiles, BK=32), counted
// vmcnt(4) + raw s_barrier (loads in flight across barriers, T3/T4), f32->bf16
// at fragment assembly, 32B-granule src-side slot swizzle (involution both sides).

#define NE     32
#define NBATCH 4096
#define KF     512
#define NF     512
#define BM     64
#define BN     64
#define BK     32            // floats per K-step (= one MFMA K)
#define NKT    (KF / BK)     // 16
#define TMAX   4
#define NCHUNK 64
#define NWG    (8 * NE * TMAX)  // 1024

typedef __attribute__((ext_vector_type(8))) short bf16x8;
typedef __attribute__((ext_vector_type(8))) float f32x8;
typedef __attribute__((ext_vector_type(4))) float f32x4;

__device__ __forceinline__ unsigned cvt2(float lo, float hi) {
    __hip_bfloat162 h = __float22bfloat162_rn(make_float2(lo, hi));
    return *reinterpret_cast<unsigned*>(&h);   // v_cvt_pk_bf16_f32
}

__device__ __forceinline__ bf16x8 pack8f(f32x8 v) {
    union { unsigned u[4]; bf16x8 b; } r;
    r.u[0] = cvt2(v[0], v[1]); r.u[1] = cvt2(v[2], v[3]);
    r.u[2] = cvt2(v[4], v[5]); r.u[3] = cvt2(v[6], v[7]);
    return r.b;
}

// async 16B global->LDS DMA; LDS dest must be wave-uniform (HW adds lane*16)
__device__ __forceinline__ void gll16(const float* gsrc, float* ldst) {
    __builtin_amdgcn_global_load_lds(
        (const __attribute__((address_space(1))) void*)gsrc,
        (__attribute__((address_space(3))) void*)ldst, 16, 0, 0);
}

// slot swizzle (16B units within a 128B row), 32B-pair-preserving involution
#define SW(r) (((r) & 3) << 1)

__global__ __launch_bounds__(256, 4)
void moe_fused(const float* __restrict__ inp,
               const int* __restrict__ gate,
               const float* __restrict__ weight,
               float* __restrict__ out) {
    // bijective XCD-chunk swizzle (1024 blocks, 8 XCDs)
    const int bid = blockIdx.x;
    const int swb = (bid & 7) * (NWG / 8) + (bid >> 3);
    const int nb    = swb & 7;
    const int y     = swb >> 3;
    const int e     = y >> 2;
    const int local = y & 3;

    __shared__ __align__(16) float lds[2][2][BM * BK];  // [buf][A/W][64 rows x 32]
    __shared__ int srow[BM];
    __shared__ int chunkinfo[NCHUNK];
    __shared__ int stotal;

    const int tid  = threadIdx.x;
    const int lane = tid & 63;
    const int wid  = tid >> 6;

    // ---- self-prep: ballot-rank tokens of expert e (r6-proven) ----
    int g[16];
#pragma unroll
    for (int i = 0; i < 16; ++i)
        g[i] = gate[(wid * 16 + i) * 64 + lane];
#pragma unroll
    for (int i = 0; i < 16; ++i) {
        unsigned long long m = __ballot(g[i] == e);
        if (lane == i) chunkinfo[wid * 16 + i] = __popcll(m);
    }
    if (tid < BM) srow[tid] = -1;
    __syncthreads();
    if (tid < NCHUNK) {
        int c = chunkinfo[tid];
        int x = c;
#pragma unroll
        for (int d = 1; d < 64; d <<= 1) {
            int u = __shfl_up(x, d, 64);
            if (lane >= d) x += u;
        }
        chunkinfo[tid] = x - c;
        if (tid == NCHUNK - 1) stotal = x;
    }
    __syncthreads();

    const int total = stotal;
    const int m0    = local * BM;
    if (m0 >= total) return;            // block-uniform exit, before any s_barrier

#pragma unroll
    for (int i = 0; i < 16; ++i) {
        unsigned long long m = __ballot(g[i] == e);
        int r = chunkinfo[wid * 16 + i] + __popcll(m & ((1ull << lane) - 1ull));
        if (g[i] == e && r >= m0 && r < m0 + BM)
            srow[r - m0] = (wid * 16 + i) * 64 + lane;
    }
    __syncthreads();                    // srow ready for DMA source addressing

    // ---- staging addresses (per-lane src, wave-uniform LDS dest) ----
    const int nblk = nb * BN;
    const float* wbase = weight + (size_t)e * (NF * KF) + (size_t)nblk * KF;

    const float* aptr[2];
    const float* wptr[2];
    int arb[2];
#pragma unroll
    for (int q = 0; q < 2; ++q) {
        arb[q] = (wid * 2 + q) * 8;               // row-block this wave-instr covers
        int r    = arb[q] + (lane >> 3);          // tile row
        int slot = (lane & 7) ^ SW(r);            // pre-swizzled source slot
        int arow = srow[r];
        aptr[q] = inp + (size_t)(arow < 0 ? 0 : arow) * KF + slot * 4;
        wptr[q] = wbase + (size_t)r * KF + slot * 4;
    }

#define STAGE(B, T) do { const int k0 = (T) * BK;                            \
    _Pragma("unroll") for (int q = 0; q < 2; ++q) {                          \
        gll16(aptr[q] + k0, &lds[B][0][arb[q] * BK]);                        \
        gll16(wptr[q] + k0, &lds[B][1][arb[q] * BK]);                        \
    } } while (0)

    const int wm = wid & 1;
    const int wn = wid >> 1;

    f32x4 acc[2][2];
#pragma unroll
    for (int mi = 0; mi < 2; ++mi)
#pragma unroll
        for (int ni = 0; ni < 2; ++ni) acc[mi][ni] = (f32x4)(0.f);

#define COMPUTE(B) do {                                                      \
    bf16x8 af[2], bw[2];                                                     \
    _Pragma("unroll") for (int mi = 0; mi < 2; ++mi) {                       \
        int r = wm * 32 + mi * 16 + (lane & 15);                             \
        int s = 2 * (lane >> 4);                                             \
        f32x8 v = *(const f32x8*)&lds[B][0][r * BK + (s ^ SW(r)) * 4];       \
        af[mi] = pack8f(v); }                                                \
    _Pragma("unroll") for (int ni = 0; ni < 2; ++ni) {                       \
        int r = wn * 32 + ni * 16 + (lane & 15);                             \
        int s = 2 * (lane >> 4);                                             \
        f32x8 v = *(const f32x8*)&lds[B][1][r * BK + (s ^ SW(r)) * 4];       \
        bw[ni] = pack8f(v); }                                                \
    _Pragma("unroll") for (int mi = 0; mi < 2; ++mi)                         \
    _Pragma("unroll") for (int ni = 0; ni < 2; ++ni)                         \
        acc[mi][ni] = __builtin_amdgcn_mfma_f32_16x16x32_bf16(               \
            af[mi], bw[ni], acc[mi][ni], 0, 0, 0); } while (0)

    // ---- pipelined K-loop: DMAs for t+1 stay in flight across barriers ----
    STAGE(0, 0);
    int cur = 0;
    for (int t = 0; t < NKT; ++t) {
        if (t + 1 < NKT) {
            STAGE(cur ^ 1, t + 1);
            asm volatile("s_waitcnt vmcnt(4)" ::: "memory");  // t's 4 DMAs done
        } else {
            asm volatile("s_waitcnt vmcnt(0)" ::: "memory");
        }
        __builtin_amdgcn_sched_barrier(0);
        __builtin_amdgcn_s_barrier();       // all waves: buf[cur] complete
        COMPUTE(cur);
        __builtin_amdgcn_sched_barrier(0);
        __builtin_amdgcn_s_barrier();       // reads done before next overwrite
        cur ^= 1;
    }
#undef STAGE
#undef COMPUTE

    // ---- epilogue: D frag col=lane&15 (n), row=(lane>>4)*4+q (m) ----
#pragma unroll
    for (int mi = 0; mi < 2; ++mi)
#pragma unroll
        for (int q = 0; q < 4; ++q) {
            int m = wm * 32 + mi * 16 + (lane >> 4) * 4 + q;
            int row = srow[m];
            if (row >= 0) {
#pragma unroll
                for (int ni = 0; ni < 2; ++ni)
                    out[(size_t)row * NF + nblk + wn * 32 + ni * 16 + (lane & 15)]
                        = acc[mi][ni][q];
            }
        }
}

extern "C" void kernel_launch(void* const* d_in, const int* in_sizes, int n_in,
                              void* d_out, int out_size, void* d_ws, size_t ws_size,
                              hipStream_t stream) {
    const float* inp    = (const float*)d_in[0];
    const int*   gate   = (const int*)d_in[1];
    const float* weight = (const float*)d_in[2];
    float*       out    = (float*)d_out;

    moe_fused<<<NWG, 256, 0, stream>>>(inp, gate, weight, out);
}

// Round 10
// 21.131 us; speedup vs baseline: 1.5602x; 1.5602x over previous
//
#include <hip/hip_runtime.h>
#include <hip/hip_bf16.h>

// MoE: out[b] = inp[b] @ weight[gate[b]].T
// inp: [4096,512] f32, gate: [4096] int, weight: [32,512,512] f32, out: [4096,512] f32
// Round 10: r6 shell; K-loop restructured so the t+1 global loads are PINNED
// above COMPUTE(t) via a volatile memory fence (r2-r9 all had the prefetch
// silently sunk to its use site: VGPR_Count=56 proves no loads were live).
// Single LDS buffer, raw s_barrier + lgkmcnt only (no vmcnt drain at barriers).

#define NE     32
#define NBATCH 4096
#define KF     512
#define NF     512
#define BM     64
#define BN     64
#define BK     64
#define NKT    (KF / BK)     // 8
#define TMAX   4
#define NCHUNK 64
#define NWG    (8 * NE * TMAX)  // 1024

typedef __attribute__((ext_vector_type(8))) short bf16x8;
typedef __attribute__((ext_vector_type(4))) float f32x4;

__device__ __forceinline__ unsigned cvt2(float lo, float hi) {
    __hip_bfloat162 h = __float22bfloat162_rn(make_float2(lo, hi));
    return *reinterpret_cast<unsigned*>(&h);   // v_cvt_pk_bf16_f32
}

// XOR swizzle within [row][64 bf16] (128B row stride); same bijection write+read.
__device__ __forceinline__ int swz(int row, int col_b) {
    return (row * 128 + col_b) ^ ((row & 7) << 4);
}

__global__ __launch_bounds__(256)
void moe_fused(const float* __restrict__ inp,
               const int* __restrict__ gate,
               const float* __restrict__ weight,
               float* __restrict__ out) {
    // bijective XCD-chunk swizzle (1024 blocks, 8 XCDs)
    const int bid = blockIdx.x;
    const int swb = (bid & 7) * (NWG / 8) + (bid >> 3);
    const int nb    = swb & 7;
    const int y     = swb >> 3;
    const int e     = y >> 2;
    const int local = y & 3;

    __shared__ __align__(16) unsigned char lds[(BM + BN) * BK * 2]; // 16KB single buf
    __shared__ int srow[BM];
    __shared__ int chunkinfo[NCHUNK];
    __shared__ int stotal;

    const int tid  = threadIdx.x;
    const int lane = tid & 63;
    const int wid  = tid >> 6;

    // ---- self-prep: ballot-rank tokens of expert e (r6-proven) ----
    int g[16];
#pragma unroll
    for (int i = 0; i < 16; ++i)
        g[i] = gate[(wid * 16 + i) * 64 + lane];
#pragma unroll
    for (int i = 0; i < 16; ++i) {
        unsigned long long m = __ballot(g[i] == e);
        if (lane == i) chunkinfo[wid * 16 + i] = __popcll(m);
    }
    if (tid < BM) srow[tid] = -1;
    __syncthreads();
    if (tid < NCHUNK) {
        int c = chunkinfo[tid];
        int x = c;
#pragma unroll
        for (int d = 1; d < 64; d <<= 1) {
            int u = __shfl_up(x, d, 64);
            if (lane >= d) x += u;
        }
        chunkinfo[tid] = x - c;
        if (tid == NCHUNK - 1) stotal = x;
    }
    __syncthreads();

    const int total = stotal;
    const int m0    = local * BM;
    if (m0 >= total) return;             // uniform exit before any raw barrier

#pragma unroll
    for (int i = 0; i < 16; ++i) {
        unsigned long long m = __ballot(g[i] == e);
        int r = chunkinfo[wid * 16 + i] + __popcll(m & ((1ull << lane) - 1ull));
        if (g[i] == e && r >= m0 && r < m0 + BM)
            srow[r - m0] = (wid * 16 + i) * 64 + lane;
    }
    __syncthreads();

    const int nblk = nb * BN;
    const int wm   = wid & 1;
    const int wn   = wid >> 1;

    int arow[4];
#pragma unroll
    for (int i = 0; i < 4; ++i) arow[i] = srow[(tid >> 4) + 16 * i];

    const float* wbase = weight + (size_t)e * (NF * KF) + (size_t)nblk * KF;

    float4 ra[4], rw[4];

#define LOAD_TILE(T) do { const int k0 = (T) * BK; const int c4 = (tid & 15) * 4;    \
    _Pragma("unroll") for (int i = 0; i < 4; ++i) {                                  \
        ra[i] = (arow[i] >= 0)                                                       \
            ? *(const float4*)(inp + (size_t)arow[i] * KF + k0 + c4)                 \
            : make_float4(0.f, 0.f, 0.f, 0.f); }                                     \
    _Pragma("unroll") for (int i = 0; i < 4; ++i) {                                  \
        int r = (tid >> 4) + 16 * i;                                                 \
        rw[i] = *(const float4*)(wbase + (size_t)r * KF + k0 + c4); } } while (0)

#define WRITE_TILE() do { const int cb = (tid & 15) * 8;                             \
    _Pragma("unroll") for (int i = 0; i < 4; ++i) {                                  \
        int r = (tid >> 4) + 16 * i;                                                 \
        uint2 p = make_uint2(cvt2(ra[i].x, ra[i].y), cvt2(ra[i].z, ra[i].w));        \
        *(uint2*)(lds + swz(r, cb)) = p; }                                           \
    _Pragma("unroll") for (int i = 0; i < 4; ++i) {                                  \
        int r = (tid >> 4) + 16 * i;                                                 \
        uint2 p = make_uint2(cvt2(rw[i].x, rw[i].y), cvt2(rw[i].z, rw[i].w));        \
        *(uint2*)(lds + 8192 + swz(r, cb)) = p; } } while (0)

    f32x4 acc[2][2];
#pragma unroll
    for (int mi = 0; mi < 2; ++mi)
#pragma unroll
        for (int ni = 0; ni < 2; ++ni) acc[mi][ni] = (f32x4)(0.f);

#define COMPUTE() do {                                                               \
    _Pragma("unroll") for (int kk = 0; kk < 2; ++kk) {                               \
        const int kb = kk * 64 + 16 * (lane >> 4);                                   \
        bf16x8 af[2], bfr[2];                                                        \
        _Pragma("unroll") for (int mi = 0; mi < 2; ++mi) {                           \
            int r = wm * 32 + mi * 16 + (lane & 15);                                 \
            af[mi] = *(const bf16x8*)(lds + swz(r, kb)); }                           \
        _Pragma("unroll") for (int ni = 0; ni < 2; ++ni) {                           \
            int r = wn * 32 + ni * 16 + (lane & 15);                                 \
            bfr[ni] = *(const bf16x8*)(lds + 8192 + swz(r, kb)); }                   \
        _Pragma("unroll") for (int mi = 0; mi < 2; ++mi)                             \
        _Pragma("unroll") for (int ni = 0; ni < 2; ++ni)                             \
            acc[mi][ni] = __builtin_amdgcn_mfma_f32_16x16x32_bf16(                   \
                af[mi], bfr[ni], acc[mi][ni], 0, 0, 0); } } while (0)

    // ---- pipelined K-loop: loads for t+1 pinned above COMPUTE(t) ----
    LOAD_TILE(0);
    for (int t = 0; t < NKT; ++t) {
        WRITE_TILE();                    // vmcnt waits inserted here, per use
        asm volatile("s_waitcnt lgkmcnt(0)" ::: "memory");
        __builtin_amdgcn_s_barrier();    // LDS tile t consistent
        if (t + 1 < NKT) LOAD_TILE(t + 1);
        asm volatile("" ::: "memory");   // PIN: loads may not sink below
        COMPUTE();                       // ds_read + MFMA hide load latency
        asm volatile("" ::: "memory");
        __builtin_amdgcn_s_barrier();    // all reads done before next WRITE
        asm volatile("" ::: "memory");
    }
#undef LOAD_TILE
#undef WRITE_TILE
#undef COMPUTE

    // ---- epilogue: D frag col=lane&15 (n), row=(lane>>4)*4+q (m) ----
#pragma unroll
    for (int mi = 0; mi < 2; ++mi)
#pragma unroll
        for (int q = 0; q < 4; ++q) {
            int m = wm * 32 + mi * 16 + (lane >> 4) * 4 + q;
            int row = srow[m];
            if (row >= 0) {
#pragma unroll
                for (int ni = 0; ni < 2; ++ni)
                    out[(size_t)row * NF + nblk + wn * 32 + ni * 16 + (lane & 15)]
                        = acc[mi][ni][q];
            }
        }
}

extern "C" void kernel_launch(void* const* d_in, const int* in_sizes, int n_in,
                              void* d_out, int out_size, void* d_ws, size_t ws_size,
                              hipStream_t stream) {
    const float* inp    = (const float*)d_in[0];
    const int*   gate   = (const int*)d_in[1];
    const float* weight = (const float*)d_in[2];
    float*       out    = (float*)d_out;

    moe_fused<<<NWG, 256, 0, stream>>>(inp, gate, weight, out);
}